// Round 1
// baseline (10657.173 us; speedup 1.0000x reference)
//
#include <hip/hip_runtime.h>
#include <math.h>

#ifndef M_PI
#define M_PI 3.14159265358979323846
#endif

#define Hd 21
#define Wd 180
#define HW 3780
#define FEAT 725760L

// ---------------------------------------------------------------------------
// Constants: Hermite basis phi[3][21], dy scalar, trig tables for lon filter.
// cb layout (floats): [0..20] phi0, [21..41] phi1, [42..62] phi2, [63] dy,
// [64..243] cos1, [244..423] sin1, [424..603] cos2, [604..783] sin2
// ---------------------------------------------------------------------------
__global__ void init_consts(float* cb) {
  int t = threadIdx.x;
  double L = sqrt(51.0 / 2.28e-11);
  if (t < 21) {
    double lat = 20.0 - 2.0 * t;
    double y = lat * 110000.0 / L;
    double e = exp(-y * y / 2.0);
    double sp = sqrt(M_PI);
    cb[t]      = (float)(e / sqrt(sp));
    cb[21 + t] = (float)(e * 2.0 * y / sqrt(2.0 * sp));
    cb[42 + t] = (float)(e * (4.0 * y * y - 2.0) / sqrt(8.0 * sp));
  }
  if (t == 63) cb[63] = (float)(2.0 * 110000.0 / L);
  if (t < 180) {
    double ang = 2.0 * M_PI * (double)t / 180.0;
    cb[64 + t]  = (float)cos(ang);
    cb[244 + t] = (float)sin(ang);
    cb[424 + t] = (float)cos(2.0 * ang);
    cb[604 + t] = (float)sin(2.0 * ang);
  }
}

// ---------------------------------------------------------------------------
// Direct 5x5 SAME conv, fp32. Block: (y, co-group-of-8, batch); 192 threads,
// thread = one x column (tid<180 active). Input channels may come from two
// concatenated sources (in1 for ci<csplit, in2 for ci>=csplit) so concats are
// never materialized. Weights indexed uniformly -> scalar loads.
// ---------------------------------------------------------------------------
template <int CIN_CHUNK>
__global__ __launch_bounds__(192) void conv5x5(
    const float* __restrict__ in1, const float* __restrict__ in2, int csplit,
    int Cin, long bstr1, long bstr2,
    const float* __restrict__ wts, const float* __restrict__ bias,
    float* __restrict__ out, long bstr_out, int cofs_out, int do_relu) {
  const int y = blockIdx.x;
  const int co0 = blockIdx.y * 8;
  const int b = blockIdx.z;
  const int tid = threadIdx.x;

  __shared__ float s_in[CIN_CHUNK][5][184];

  float acc[8];
#pragma unroll
  for (int i = 0; i < 8; i++) acc[i] = 0.f;

  for (int cc0 = 0; cc0 < Cin; cc0 += CIN_CHUNK) {
    __syncthreads();
    // stage input rows y-2..y+2 for CIN_CHUNK channels, cols -2..181
    for (int idx = tid; idx < CIN_CHUNK * 5 * 184; idx += 192) {
      int xcol = idx % 184;
      int rem = idx / 184;
      int dy = rem % 5;
      int ci = rem / 5;
      int ci_abs = cc0 + ci;
      int yin = y + dy - 2;
      int xin = xcol - 2;
      float v = 0.f;
      if (yin >= 0 && yin < Hd && xin >= 0 && xin < Wd) {
        const float* src;
        if (ci_abs < csplit)
          src = in1 + (long)b * bstr1 + (long)ci_abs * HW;
        else
          src = in2 + (long)b * bstr2 + (long)(ci_abs - csplit) * HW;
        v = src[yin * Wd + xin];
      }
      s_in[ci][dy][xcol] = v;
    }
    __syncthreads();

    if (tid < Wd) {
#pragma unroll
      for (int ci = 0; ci < CIN_CHUNK; ci++) {
#pragma unroll
        for (int dy = 0; dy < 5; dy++) {
          float i0 = s_in[ci][dy][tid + 0];
          float i1 = s_in[ci][dy][tid + 1];
          float i2 = s_in[ci][dy][tid + 2];
          float i3 = s_in[ci][dy][tid + 3];
          float i4 = s_in[ci][dy][tid + 4];
#pragma unroll
          for (int cc = 0; cc < 8; cc++) {
            const float* w =
                wts + ((long)(co0 + cc) * Cin + (cc0 + ci)) * 25 + dy * 5;
            acc[cc] = fmaf(i0, w[0], acc[cc]);
            acc[cc] = fmaf(i1, w[1], acc[cc]);
            acc[cc] = fmaf(i2, w[2], acc[cc]);
            acc[cc] = fmaf(i3, w[3], acc[cc]);
            acc[cc] = fmaf(i4, w[4], acc[cc]);
          }
        }
      }
    }
  }

  if (tid < Wd) {
#pragma unroll
    for (int cc = 0; cc < 8; cc++) {
      float v = acc[cc] + bias[co0 + cc];
      if (do_relu) v = fmaxf(v, 0.f);
      out[(long)b * bstr_out + (long)(cofs_out + co0 + cc) * HW + y * Wd + tid] = v;
    }
  }
}

// ---------------------------------------------------------------------------
// Strided per-batch float4 copy (x2 -> x6 channels 128..191)
// ---------------------------------------------------------------------------
__global__ void copy_b(const float* __restrict__ src, long sstr,
                       float* __restrict__ dst, long dstr, int nquads) {
  int b = blockIdx.y;
  int q = blockIdx.x * blockDim.x + threadIdx.x;
  if (q < nquads)
    *((float4*)(dst + (long)b * dstr) + q) =
        *((const float4*)(src + (long)b * sstr) + q);
}

// ---------------------------------------------------------------------------
// Fused Hermite-residual (lat) + low-frequency-removal (lon) filter.
// One block per (b,c) slab of [21][180], in place.
// irfft(zero bins 0..2)  ==  x - (S0 + 2*(A1 c1 + B1 s1 + A2 c2 + B2 s2))/180
// ---------------------------------------------------------------------------
__global__ __launch_bounds__(192) void filter_kernel(float* __restrict__ data,
                                                     const float* __restrict__ cb) {
  __shared__ float s[21][180];
  __shared__ float strig[4][180];
  __shared__ float ssum[21][8];
  const int tid = threadIdx.x;
  float* p = data + (size_t)blockIdx.x * HW;

  for (int i = tid; i < HW; i += 192) ((float*)s)[i] = p[i];
  for (int i = tid; i < 720; i += 192) ((float*)strig)[i] = cb[64 + i];
  __syncthreads();

  // Hermite residual along lat (per column)
  if (tid < Wd) {
    float um0 = 0.f, um1 = 0.f, um2 = 0.f;
#pragma unroll
    for (int y = 0; y < 21; y++) {
      float v = s[y][tid];
      um0 = fmaf(v, cb[y], um0);
      um1 = fmaf(v, cb[21 + y], um1);
      um2 = fmaf(v, cb[42 + y], um2);
    }
    const float dyc = cb[63];
    um0 *= dyc; um1 *= dyc; um2 *= dyc;
#pragma unroll
    for (int y = 0; y < 21; y++) {
      float pr = um0 * cb[y] + um1 * cb[21 + y] + um2 * cb[42 + y];
      s[y][tid] -= pr;
    }
  }
  __syncthreads();

  // per-row spectral sums: 21 rows x 8 lanes each
  if (tid < 168) {
    int g = tid >> 3, l = tid & 7;
    float S0 = 0.f, A1 = 0.f, B1 = 0.f, A2 = 0.f, B2 = 0.f;
    for (int x = l; x < Wd; x += 8) {
      float v = s[g][x];
      S0 += v;
      A1 = fmaf(v, strig[0][x], A1);
      B1 = fmaf(v, strig[1][x], B1);
      A2 = fmaf(v, strig[2][x], A2);
      B2 = fmaf(v, strig[3][x], B2);
    }
#pragma unroll
    for (int ofs = 1; ofs <= 4; ofs <<= 1) {
      S0 += __shfl_xor(S0, ofs);
      A1 += __shfl_xor(A1, ofs);
      B1 += __shfl_xor(B1, ofs);
      A2 += __shfl_xor(A2, ofs);
      B2 += __shfl_xor(B2, ofs);
    }
    if (l == 0) {
      ssum[g][0] = S0; ssum[g][1] = A1; ssum[g][2] = B1;
      ssum[g][3] = A2; ssum[g][4] = B2;
    }
  }
  __syncthreads();

  if (tid < Wd) {
    float c1 = strig[0][tid], s1 = strig[1][tid];
    float c2 = strig[2][tid], s2 = strig[3][tid];
#pragma unroll
    for (int y = 0; y < 21; y++) {
      float corr = ssum[y][0] +
                   2.f * (ssum[y][1] * c1 + ssum[y][2] * s1 +
                          ssum[y][3] * c2 + ssum[y][4] * s2);
      p[y * Wd + tid] = s[y][tid] - corr * (1.f / 180.f);
    }
  }
}

// ---------------------------------------------------------------------------
// FC1: h1[32,500] += x[32,725760] @ w[500,725760]^T   (split-K, atomics)
// 1-wave blocks; block tile 32b x 128o; thread tile 8b x 8o; KC=32.
// grid = (4 o-tiles, 840 k-splits); each block does 27 KC-chunks.
// ---------------------------------------------------------------------------
__global__ __launch_bounds__(64) void fc1_kernel(const float* __restrict__ x,
                                                 const float* __restrict__ w,
                                                 float* __restrict__ h1) {
  __shared__ float xs[32][68];    // [b][k]  (pad 68 = 4-float aligned)
  __shared__ float wsd[32][132];  // [k][o]  transposed (pad 132)
  const int t = threadIdx.x;
  const int o0 = blockIdx.x * 128;
  const long kbase = (long)blockIdx.y * (27L * 32L);
  const int bg = t >> 4;  // 0..3  -> b = bg*8 + bi
  const int og = t & 15;  // 0..15 -> o = o0 + og*8 + oi

  float acc[8][8];
#pragma unroll
  for (int i = 0; i < 8; i++)
#pragma unroll
    for (int j = 0; j < 8; j++) acc[i][j] = 0.f;

  for (int ch = 0; ch < 27; ch++) {
    long k0 = kbase + ch * 32;
    __syncthreads();
    // stage x: 32b x 32k (256 quads, 4/thread)
#pragma unroll
    for (int i = 0; i < 4; i++) {
      int q = i * 64 + t;
      int b = q >> 3, kq = q & 7;
      float4 v = *(const float4*)(x + (long)b * FEAT + k0 + kq * 4);
      *(float4*)(&xs[b][kq * 4]) = v;
    }
    // stage w transposed: 128o x 32k (1024 quads, 16/thread)
#pragma unroll
    for (int i = 0; i < 16; i++) {
      int q = i * 64 + t;
      int o = q >> 3, kq = q & 7;
      float4 v = make_float4(0.f, 0.f, 0.f, 0.f);
      if (o0 + o < 500)
        v = *(const float4*)(w + (long)(o0 + o) * FEAT + k0 + kq * 4);
      wsd[kq * 4 + 0][o] = v.x;
      wsd[kq * 4 + 1][o] = v.y;
      wsd[kq * 4 + 2][o] = v.z;
      wsd[kq * 4 + 3][o] = v.w;
    }
    __syncthreads();

#pragma unroll
    for (int kq = 0; kq < 8; kq++) {
      float xv[8][4];
#pragma unroll
      for (int bi = 0; bi < 8; bi++)
        *(float4*)xv[bi] = *(const float4*)(&xs[bg * 8 + bi][kq * 4]);
#pragma unroll
      for (int kk = 0; kk < 4; kk++) {
        float wv[8];
        *(float4*)&wv[0] = *(const float4*)(&wsd[kq * 4 + kk][og * 8]);
        *(float4*)&wv[4] = *(const float4*)(&wsd[kq * 4 + kk][og * 8 + 4]);
#pragma unroll
        for (int bi = 0; bi < 8; bi++)
#pragma unroll
          for (int oi = 0; oi < 8; oi++)
            acc[bi][oi] = fmaf(xv[bi][kk], wv[oi], acc[bi][oi]);
      }
    }
  }

#pragma unroll
  for (int bi = 0; bi < 8; bi++)
#pragma unroll
    for (int oi = 0; oi < 8; oi++) {
      int o = o0 + og * 8 + oi;
      if (o < 500)
        atomicAdd(&h1[(long)(bg * 8 + bi) * 500 + o], acc[bi][oi]);
    }
}

__global__ void fc1_init(const float* __restrict__ bias, float* __restrict__ h1) {
  int idx = blockIdx.x * blockDim.x + threadIdx.x;
  if (idx < 32 * 500) h1[idx] = bias[idx % 500];
}

// ---------------------------------------------------------------------------
// Small FC: one thread per (b,o); optional relu on input read and output.
// ---------------------------------------------------------------------------
__global__ void fc_small(const float* __restrict__ in, const float* __restrict__ w,
                         const float* __restrict__ bias, float* __restrict__ out,
                         int B, int K, int O, int relu_in, int relu_out) {
  int idx = blockIdx.x * blockDim.x + threadIdx.x;
  if (idx >= B * O) return;
  int b = idx / O, o = idx % O;
  const float* ip = in + (long)b * K;
  const float* wp = w + (long)o * K;
  float s = bias[o];
  for (int k = 0; k < K; k++) {
    float v = ip[k];
    if (relu_in) v = fmaxf(v, 0.f);
    s = fmaf(v, wp[k], s);
  }
  if (relu_out) s = fmaxf(s, 0.f);
  out[(long)b * O + o] = s;
}

// ---------------------------------------------------------------------------
extern "C" void kernel_launch(void* const* d_in, const int* in_sizes, int n_in,
                              void* d_out, int out_size, void* d_ws, size_t ws_size,
                              hipStream_t stream) {
  const float* x    = (const float*)d_in[0];
  const float* w_in = (const float*)d_in[1];
  const float* b_in = (const float*)d_in[2];
  const float* w1   = (const float*)d_in[3];
  const float* b1   = (const float*)d_in[4];
  const float* w2   = (const float*)d_in[5];
  const float* b2   = (const float*)d_in[6];
  const float* w3   = (const float*)d_in[7];
  const float* b3   = (const float*)d_in[8];
  const float* w4   = (const float*)d_in[9];
  const float* b4   = (const float*)d_in[10];
  const float* w5   = (const float*)d_in[11];
  const float* b5   = (const float*)d_in[12];
  const float* wfc1 = (const float*)d_in[13];
  const float* bfc1 = (const float*)d_in[14];
  const float* wfc2 = (const float*)d_in[15];
  const float* bfc2 = (const float*)d_in[16];
  const float* wfc3 = (const float*)d_in[17];
  const float* bfc3 = (const float*)d_in[18];
  const float* wfc4 = (const float*)d_in[19];
  const float* bfc4 = (const float*)d_in[20];

  float* ws = (float*)d_ws;
  const long F = 7741440L;  // 32*64*3780 floats (one 64-ch activation)
  float* cb = ws;           // 1024 floats
  float* A  = ws + 1024;    // x1, later x4 (conv3 out)
  float* Bb = A + F;        // x2
  float* Cc = Bb + F;       // x3
  float* Dd = Cc + F;       // conv4 out (relu)
  float* Ee = Dd + F;       // x6 [32,192,3780] (filtered in place)
  float* h1 = Ee + 3 * F;   // 16000
  float* h2 = h1 + 16000;   // 6400
  float* h3 = h2 + 6400;    // 1600

  init_consts<<<1, 256, 0, stream>>>(cb);

  // conv_in: 1 -> 64
  conv5x5<1><<<dim3(21, 8, 32), 192, 0, stream>>>(
      x, x, 1, 1, (long)HW, (long)HW, w_in, b_in, A, 64L * HW, 0, 1);
  // conv1: 64 -> 64 (x1 -> x2)
  conv5x5<4><<<dim3(21, 8, 32), 192, 0, stream>>>(
      A, A, 64, 64, 64L * HW, 64L * HW, w1, b1, Bb, 64L * HW, 0, 1);
  // conv2: x2 -> x3
  conv5x5<4><<<dim3(21, 8, 32), 192, 0, stream>>>(
      Bb, Bb, 64, 64, 64L * HW, 64L * HW, w2, b2, Cc, 64L * HW, 0, 1);
  // conv3: x3 -> x4 (reuse A)
  conv5x5<4><<<dim3(21, 8, 32), 192, 0, stream>>>(
      Cc, Cc, 64, 64, 64L * HW, 64L * HW, w3, b3, A, 64L * HW, 0, 1);
  // conv4: x4 -> D (relu)
  conv5x5<4><<<dim3(21, 8, 32), 192, 0, stream>>>(
      A, A, 64, 64, 64L * HW, 64L * HW, w4, b4, Dd, 64L * HW, 0, 1);
  // conv5: concat(D, x3) 128 -> 128, into x6[:, :128], relu
  conv5x5<4><<<dim3(21, 16, 32), 192, 0, stream>>>(
      Dd, Cc, 64, 128, 64L * HW, 64L * HW, w5, b5, Ee, 192L * HW, 0, 1);
  // x2 -> x6[:, 128:192]
  copy_b<<<dim3(237, 32), 256, 0, stream>>>(Bb, 64L * HW, Ee + 128L * HW,
                                            192L * HW, 60480);
  // Hermite + spectral high-pass, in place on x6
  filter_kernel<<<32 * 192, 192, 0, stream>>>(Ee, cb);

  // FC1 (split-K + atomics), then small FCs
  fc1_init<<<63, 256, 0, stream>>>(bfc1, h1);
  fc1_kernel<<<dim3(4, 840), 64, 0, stream>>>(Ee, wfc1, h1);
  fc_small<<<25, 256, 0, stream>>>(h1, wfc2, bfc2, h2, 32, 500, 200, 1, 1);
  fc_small<<<7, 256, 0, stream>>>(h2, wfc3, bfc3, h3, 32, 200, 50, 0, 1);
  fc_small<<<1, 64, 0, stream>>>(h3, wfc4, bfc4, (float*)d_out, 32, 50, 2, 0, 0);
}